// Round 3
// baseline (262.786 us; speedup 1.0000x reference)
//
#include <hip/hip_runtime.h>
#include <hip/hip_bf16.h>

constexpr int BATCH = 4;
constexpr int SEQ   = 2048;
constexpr int DIM   = 768;
constexpr int NH    = 12;
constexpr int HDIM  = 64;

typedef __attribute__((ext_vector_type(8))) short bf16x8;
typedef __attribute__((ext_vector_type(4))) float f32x4;
typedef __attribute__((ext_vector_type(4))) short s16x4;

__device__ inline short f2bf(float f) {
    union { float f; unsigned u; } v; v.f = f;
    unsigned r = (v.u + 0x7fff + ((v.u >> 16) & 1)) >> 16;  // RNE
    return (short)r;
}

__device__ inline unsigned pack_bf16x2(float a, float b) {
    union { __hip_bfloat162 h; unsigned u; } c;
    c.h = __float22bfloat162_rn(make_float2(a, b));
    return c.u;
}

__device__ inline float fast_exp2(float x) {
#if __has_builtin(__builtin_amdgcn_exp2f)
    return __builtin_amdgcn_exp2f(x);
#else
    return __expf(x * 0.6931471805599453f);
#endif
}

__device__ inline void gld16(const short* g, short* l) {
    __builtin_amdgcn_global_load_lds(
        (const __attribute__((address_space(1))) void*)g,
        (__attribute__((address_space(3))) void*)l, 16, 0, 0);
}

__device__ inline bool ctx_at(const void* p, bool isU8, int idx) {
    return isU8 ? (((const unsigned char*)p)[idx] != 0)
                : (((const int*)p)[idx] != 0);
}

// ---------------------------------------------------------------------------
// prep: fused fp32->bf16 casts (x, Wq, Wk, Wv, Wo) + mask-layout detect.
// ---------------------------------------------------------------------------
__global__ __launch_bounds__(256) void prep_kernel(
    const float* __restrict__ x,  const float* __restrict__ Wq,
    const float* __restrict__ Wk, const float* __restrict__ Wv,
    const float* __restrict__ Wo,
    short* __restrict__ xb,  short* __restrict__ Wqb,
    short* __restrict__ Wkb, short* __restrict__ Wvb,
    short* __restrict__ Wob,
    const unsigned char* __restrict__ ctxm, int ctxbytes, int* __restrict__ flag) {
    const int blk = blockIdx.x;
    constexpr int XBLK = (BATCH * SEQ * DIM / 4) / 256;  // 6144
    constexpr int WBLK = (DIM * DIM / 4) / 256;          // 576

    if (blk == XBLK + 4 * WBLK) {
        __shared__ int cnt;
        if (threadIdx.x == 0) cnt = 0;
        __syncthreads();
        int local = 0;
        for (int i = threadIdx.x; i < ctxbytes; i += 256)
            if ((i & 3) != 0 && ctxm[i] != 0) local++;
        atomicAdd(&cnt, local);
        __syncthreads();
        if (threadIdx.x == 0) *flag = (cnt > 0) ? 1 : 0;
        return;
    }

    const float* src; short* dst; int i;
    if (blk < XBLK) {
        src = x; dst = xb;
        i = blk * 256 + threadIdx.x;
    } else {
        const int r = blk - XBLK;
        const int w = r / WBLK;
        src = (w == 0) ? Wq : (w == 1) ? Wk : (w == 2) ? Wv : Wo;
        dst = (w == 0) ? Wqb : (w == 1) ? Wkb : (w == 2) ? Wvb : Wob;
        i = (r - w * WBLK) * 256 + threadIdx.x;
    }
    float4 v = ((const float4*)src)[i];
    s16x4 o;
    o.x = f2bf(v.x); o.y = f2bf(v.y); o.z = f2bf(v.z); o.w = f2bf(v.w);
    ((s16x4*)dst)[i] = o;
}

// ---------------------------------------------------------------------------
// m97-style MFMA GEMM. VT=true: blockIdx.z==2 (the V projection) stores
// directly in the attention's transposed+permuted Vtg layout:
//   Vtg[((b*NH+h)*64 + d)*SEQ + tile*64 + pos(key)]
// pos(key) inverse map (verified vs vtrans forward map):
//   pos = (k&32) | (k&16 ? ((((k>>2)&3)^2)<<3)+4 : ((k>>2)&3)<<3) | (k&3)
// In epilogue coords (k = mt*16 + quad*4 + reg):
//   p_base = ((mt&2)<<4) + (mt&1 ? ((quad^2)<<3)+4 : quad<<3), pos = p_base+reg
// so each (mt,nt) writes one s16x4 (4 consecutive shorts).
// ---------------------------------------------------------------------------
template <bool BF16OUT, bool VT>
__global__ __launch_bounds__(256) void gemm_mfma(
    const short* __restrict__ A,
    const short* __restrict__ W0, const float* __restrict__ bias0, void* __restrict__ C0,
    const short* __restrict__ W1, const float* __restrict__ bias1, void* __restrict__ C1,
    const short* __restrict__ W2, const float* __restrict__ bias2, void* __restrict__ C2,
    float scale0) {
    constexpr int N  = DIM;
    constexpr int Kd = DIM;

    const short* W; const float* bias; void* C; float scale;
    if (blockIdx.z == 0)      { W = W0; bias = bias0; C = C0; scale = scale0; }
    else if (blockIdx.z == 1) { W = W1; bias = bias1; C = C1; scale = 1.f; }
    else                      { W = W2; bias = bias2; C = C2; scale = 1.f; }

    const int tid  = threadIdx.x;
    const int wave = tid >> 6;
    const int lane = tid & 63;
    const int quad = lane >> 4;
    const int l16  = lane & 15;
    const int wm   = wave & 1;
    const int wn   = wave >> 1;
    const int m0   = blockIdx.y * 128;
    const int n0   = blockIdx.x * 128;

    __shared__ short As[128 * 32];
    __shared__ short Bs[128 * 32];

    const int srow = tid >> 2;
    const int skq  = tid & 3;
    const short* Ag = A + (size_t)(m0 + srow) * Kd + skq * 8;
    const short* Wg = W + (size_t)(n0 + srow) * Kd + skq * 8;
    short* AsP = As + srow * 32 + skq * 8;
    short* BsP = Bs + srow * 32 + skq * 8;

    f32x4 acc[4][4] = {};

    for (int kt = 0; kt < Kd; kt += 32) {
        __syncthreads();
        gld16(Ag + kt,                AsP);
        gld16(Ag + kt + 64 * Kd,      AsP + 64 * 32);
        gld16(Wg + kt,                BsP);
        gld16(Wg + kt + 64 * Kd,      BsP + 64 * 32);
        __syncthreads();

        bf16x8 af[4], bfr[4];
#pragma unroll
        for (int mt = 0; mt < 4; ++mt)
            af[mt] = *(const bf16x8*)&As[(wm * 64 + mt * 16 + l16) * 32 + quad * 8];
#pragma unroll
        for (int nt = 0; nt < 4; ++nt)
            bfr[nt] = *(const bf16x8*)&Bs[(wn * 64 + nt * 16 + l16) * 32 + quad * 8];
#pragma unroll
        for (int mt = 0; mt < 4; ++mt)
#pragma unroll
            for (int nt = 0; nt < 4; ++nt)
                acc[mt][nt] = __builtin_amdgcn_mfma_f32_16x16x32_bf16(
                    af[mt], bfr[nt], acc[mt][nt], 0, 0, 0);
    }

    float bv[4];
#pragma unroll
    for (int nt = 0; nt < 4; ++nt) bv[nt] = bias[n0 + wn * 64 + nt * 16 + l16];

    if (VT && blockIdx.z == 2) {
        // V projection: store transposed+permuted for the attention kernel.
        const int tok0 = m0 + wm * 64;               // multiple of 64
        const int bb   = tok0 >> 11;                 // / SEQ
        const int tt   = (tok0 & (SEQ - 1)) >> 6;    // key tile
        short* Vt = (short*)C;
#pragma unroll
        for (int mt = 0; mt < 4; ++mt) {
            const int p_base = ((mt & 2) << 4) +
                               ((mt & 1) ? (((quad ^ 2) << 3) + 4) : (quad << 3));
#pragma unroll
            for (int nt = 0; nt < 4; ++nt) {
                const int n    = n0 + wn * 64 + nt * 16 + l16;
                const int hh   = n >> 6;
                const int dcol = n & 63;
                s16x4 o;
#pragma unroll
                for (int reg = 0; reg < 4; ++reg)
                    o[reg] = f2bf(acc[mt][nt][reg] + bv[nt]);
                *(s16x4*)(Vt + ((size_t)((bb * NH + hh) * HDIM + dcol)) * SEQ
                          + tt * 64 + p_base) = o;
            }
        }
        return;
    }

#pragma unroll
    for (int mt = 0; mt < 4; ++mt)
#pragma unroll
        for (int nt = 0; nt < 4; ++nt)
#pragma unroll
            for (int reg = 0; reg < 4; ++reg) {
                const int m = m0 + wm * 64 + mt * 16 + quad * 4 + reg;
                const int n = n0 + wn * 64 + nt * 16 + l16;
                const float v = (acc[mt][nt][reg] + bv[nt]) * scale;
                if (BF16OUT) ((short*)C)[(size_t)m * N + n] = f2bf(v);
                else         ((float*)C)[(size_t)m * N + n] = v;
            }
}

// ---------------------------------------------------------------------------
// MFMA flash attention v9 = v8 (register P, 3-deep LDS, counted vmcnt, XCD
// swizzle) + CROSS-TILE SOFTWARE PIPELINE: QK^T(t+1) is computed in the same
// scheduler region as softmax(t)+PV(t), so the matrix pipe chews tile t+1's
// scores while the trans/VALU/LDS pipes chew tile t's softmax. Score regs are
// double-buffered (sA/sB) with a 2x-unrolled loop -> all static indexing.
// Buffer roles at iter t: PV reads buf[t%3], QK reads buf[(t+1)%3], stage
// writes buf[(t+2)%3] -- all distinct mod 3. vmcnt(4) after stage(t+2)
// guarantees tiles t AND t+1 are in LDS (FIFO counter), barrier makes it
// true for all waves.
// ---------------------------------------------------------------------------
__global__ __launch_bounds__(256, 3) void attn_mfma9(
    const short* __restrict__ Qb, const short* __restrict__ Kb,
    const short* __restrict__ Vtg, const void* __restrict__ ctxp,
    const int* __restrict__ flagp, short* __restrict__ Ob) {
    // XCD-chunked swizzle: 768 blocks = 8 XCDs x 96; q-chunk fastest so each
    // XCD owns 6 complete (b,h) K/V panels.
    const int swz  = (blockIdx.x & 7) * 96 + (blockIdx.x >> 3);
    const int qc   = swz & 15;
    const int h    = (swz >> 4) % NH;
    const int b    = swz / (16 * NH);
    const int q0   = qc * 128;
    const int tid  = threadIdx.x;
    const int wave = tid >> 6;
    const int lane = tid & 63;
    const int quad = lane >> 4;
    const int l16  = lane & 15;
    const bool isU8 = (*flagp != 0);

    __shared__ short Ks[3][64 * 64];   // 8 KB x3, swizzled chunks
    __shared__ short Vs[3][64 * 64];   // 8 KB x3, swizzled chunks (key-permuted)

    const short* Kg = Kb + (size_t)b * SEQ * DIM + h * HDIM;
    const short* Vg = Vtg + (size_t)(b * NH + h) * HDIM * SEQ;

    // Staging map: thread covers rows r0 and r0+32, chunk j0 (swizzle).
    const int r0 = tid >> 3;
    const int j0 = (tid & 7) ^ (r0 & 7);
    const int sw = l16 & 7;            // fragment-read swizzle component

    // Q fragments: rows q0 + wave*32 + rg*16 + l16 (consumed as B-operand).
    bf16x8 qf[2][2];
#pragma unroll
    for (int rg = 0; rg < 2; ++rg) {
        const short* qp = Qb + (size_t)(b * SEQ + q0 + wave * 32 + rg * 16 + l16) * DIM
                        + h * HDIM + quad * 8;
        qf[rg][0] = *(const bf16x8*)qp;
        qf[rg][1] = *(const bf16x8*)(qp + 32);
    }

    // Query mask per rg: q = q0 + wave*32 + rg*16 + l16 (lane-column indexed).
    unsigned nmb[2];
#pragma unroll
    for (int rg = 0; rg < 2; ++rg)
        nmb[rg] = ctx_at(ctxp, isU8,
            b * SEQ + q0 + wave * 32 + rg * 16 + l16) ? 0u : 0xFFFFFFFFu;

    constexpr int NT = SEQ / 64;
    // Pre-gather key ctx bits: bit t = ctx[b*SEQ + t*64 + lane].
    unsigned kbits = 0;
#pragma unroll
    for (int t = 0; t < NT; ++t)
        kbits |= (ctx_at(ctxp, isU8, b * SEQ + t * 64 + lane) ? 1u : 0u) << t;

    bf16x8 ones;
#pragma unroll
    for (int i = 0; i < 8; ++i) ones[i] = (short)0x3F80;  // bf16 1.0

    f32x4 accl[2] = {};
    f32x4 acc[2][4] = {};

    auto stage = [&](int t) {
        short* KD = Ks[t % 3];
        short* VD = Vs[t % 3];
        const int kn = t * 64;
        gld16(Kg + (size_t)(kn + r0) * DIM + j0 * 8,      KD + tid * 8);
        gld16(Kg + (size_t)(kn + r0 + 32) * DIM + j0 * 8, KD + (tid + 256) * 8);
        gld16(Vg + (size_t)r0 * SEQ + kn + j0 * 8,        VD + tid * 8);
        gld16(Vg + (size_t)(r0 + 32) * SEQ + kn + j0 * 8, VD + (tid + 256) * 8);
    };

    // S^T = K @ Q^T into sd: C[key=g*16+quad*4+reg][q=rg*16+l16].
    auto qk = [&](const short* BK, f32x4 (&sd)[4][2]) {
#pragma unroll
        for (int g = 0; g < 4; ++g) { sd[g][0] = (f32x4){}; sd[g][1] = (f32x4){}; }
        __builtin_amdgcn_s_setprio(1);
#pragma unroll
        for (int ks = 0; ks < 2; ++ks) {
            bf16x8 kf[4];
#pragma unroll
            for (int g = 0; g < 4; ++g)
                kf[g] = *(const bf16x8*)
                    &BK[(g * 16 + l16) * 64 + (((ks * 4 + quad) ^ sw)) * 8];
#pragma unroll
            for (int g = 0; g < 4; ++g) {
                sd[g][0] = __builtin_amdgcn_mfma_f32_16x16x32_bf16(kf[g], qf[0][ks], sd[g][0], 0, 0, 0);
                sd[g][1] = __builtin_amdgcn_mfma_f32_16x16x32_bf16(kf[g], qf[1][ks], sd[g][1], 0, 0, 0);
            }
        }
        __builtin_amdgcn_s_setprio(0);
    };

    // softmax(tile t scores in sp) + O += P@V, l += P@1 from buf BV.
    auto sm_pv = [&](f32x4 (&sp)[4][2], int t, const short* BV) {
        const unsigned long long kmask = __ballot((kbits >> t) & 1u);
        unsigned mw[2][4];
#pragma unroll
        for (int ks = 0; ks < 2; ++ks)
#pragma unroll
            for (int w = 0; w < 4; ++w) {
                const int base = 32 * ks + ((w >> 1) & 1) * 16 + quad * 4 + (w & 1) * 2;
                const unsigned two = (unsigned)(kmask >> base) & 3u;
                mw[ks][w] = ((two & 1u) ? 0x0000FFFFu : 0u) |
                            ((two & 2u) ? 0xFFFF0000u : 0u);
            }

        bf16x8 pa[2][2];
#pragma unroll
        for (int rg = 0; rg < 2; ++rg) {
            const unsigned nm = nmb[rg];
#pragma unroll
            for (int ks = 0; ks < 2; ++ks) {
                const int g0 = 2 * ks, g1 = 2 * ks + 1;
                const float e0 = fast_exp2(sp[g0][rg][0]);
                const float e1 = fast_exp2(sp[g0][rg][1]);
                const float e2 = fast_exp2(sp[g0][rg][2]);
                const float e3 = fast_exp2(sp[g0][rg][3]);
                const float e4 = fast_exp2(sp[g1][rg][0]);
                const float e5 = fast_exp2(sp[g1][rg][1]);
                const float e6 = fast_exp2(sp[g1][rg][2]);
                const float e7 = fast_exp2(sp[g1][rg][3]);
                const unsigned wA0 = pack_bf16x2(e0, e1) & (nm | mw[ks][0]);
                const unsigned wA1 = pack_bf16x2(e2, e3) & (nm | mw[ks][1]);
                const unsigned wB0 = pack_bf16x2(e4, e5) & (nm | mw[ks][2]);
                const unsigned wB1 = pack_bf16x2(e6, e7) & (nm | mw[ks][3]);
                // Partner quad (lane^32) exchange completes k-slots 4..7.
                const unsigned pB0 = (unsigned)__shfl((int)wB0, lane ^ 32);
                const unsigned pB1 = (unsigned)__shfl((int)wB1, lane ^ 32);
                union { bf16x8 v; unsigned u[4]; } tb;
                tb.u[0] = wA0; tb.u[1] = wA1; tb.u[2] = pB0; tb.u[3] = pB1;
                pa[rg][ks] = tb.v;
            }
        }

        __builtin_amdgcn_s_setprio(1);
#pragma unroll
        for (int ks = 0; ks < 2; ++ks) {
            accl[0] = __builtin_amdgcn_mfma_f32_16x16x32_bf16(pa[0][ks], ones, accl[0], 0, 0, 0);
            accl[1] = __builtin_amdgcn_mfma_f32_16x16x32_bf16(pa[1][ks], ones, accl[1], 0, 0, 0);
#pragma unroll
            for (int dt = 0; dt < 4; ++dt) {
                bf16x8 vf = *(const bf16x8*)
                    &BV[(dt * 16 + l16) * 64 + (((ks * 4 + quad) ^ sw)) * 8];
                acc[0][dt] = __builtin_amdgcn_mfma_f32_16x16x32_bf16(pa[0][ks], vf, acc[0][dt], 0, 0, 0);
                acc[1][dt] = __builtin_amdgcn_mfma_f32_16x16x32_bf16(pa[1][ks], vf, acc[1][dt], 0, 0, 0);
            }
        }
        __builtin_amdgcn_s_setprio(0);
    };

    f32x4 sA[4][2], sB[4][2];

    // Prologue: stage tiles 0,1; wait tile 0 (vmcnt(4): all but stage(1)'s 4
    // loads retired); compute QK(0).
    stage(0);
    stage(1);
    asm volatile("s_waitcnt vmcnt(4)" ::: "memory");
    __builtin_amdgcn_sched_barrier(0);
    __builtin_amdgcn_s_barrier();
    __builtin_amdgcn_sched_barrier(0);
    qk(Ks[0], sA);

    auto body = [&](int t, f32x4 (&prev)[4][2], f32x4 (&next)[4][2]) {
        __builtin_amdgcn_s_barrier();          // readers of buf[(t+2)%3] done
        __builtin_amdgcn_sched_barrier(0);
        if (t + 2 < NT) stage(t + 2);
        if (t < NT - 2) { asm volatile("s_waitcnt vmcnt(4)" ::: "memory"); }
        else            { asm volatile("s_waitcnt vmcnt(0)" ::: "memory"); }
        __builtin_amdgcn_sched_barrier(0);
        __builtin_amdgcn_s_barrier();          // tiles t, t+1 in LDS, all waves
        __builtin_amdgcn_sched_barrier(0);
        if (t + 1 < NT) qk(Ks[(t + 1) % 3], next);   // overlaps softmax below
        sm_pv(prev, t, Vs[t % 3]);
    };

    for (int t2 = 0; t2 < NT; t2 += 2) {
        body(t2,     sA, sB);
        body(t2 + 1, sB, sA);
    }

    float inv[2][4];
#pragma unroll
    for (int rg = 0; rg < 2; ++rg)
#pragma unroll
        for (int reg = 0; reg < 4; ++reg)
            inv[rg][reg] = 1.f / accl[rg][reg];

#pragma unroll
    for (int rg = 0; rg < 2; ++rg)
#pragma unroll
        for (int dt = 0; dt < 4; ++dt)
#pragma unroll
            for (int reg = 0; reg < 4; ++reg) {
                const int q = q0 + wave * 32 + rg * 16 + quad * 4 + reg;
                Ob[(size_t)(b * SEQ + q) * DIM + h * HDIM + dt * 16 + l16] =
                    f2bf(acc[rg][dt][reg] * inv[rg][reg]);
            }
}

// ---------------------------------------------------------------------------
// kernel_launch
// ---------------------------------------------------------------------------
extern "C" void kernel_launch(void* const* d_in, const int* in_sizes, int n_in,
                              void* d_out, int out_size, void* d_ws, size_t ws_size,
                              hipStream_t stream) {
    const float* x   = (const float*)d_in[0];
    const void*  ctx = d_in[1];
    const float* Wq  = (const float*)d_in[2];
    const float* bq  = (const float*)d_in[3];
    const float* Wk  = (const float*)d_in[4];
    const float* bk  = (const float*)d_in[5];
    const float* Wv  = (const float*)d_in[6];
    const float* bv  = (const float*)d_in[7];
    const float* Wo  = (const float*)d_in[8];
    const float* bo  = (const float*)d_in[9];
    float* out = (float*)d_out;

    char* ws = (char*)d_ws;
    int* flag = (int*)ws;
    const size_t bufbf = (size_t)BATCH * SEQ * DIM * sizeof(short);  // 12.6 MB
    const size_t wbuf  = (size_t)DIM * DIM * sizeof(short);          // 1.18 MB
    short* xb  = (short*)(ws + 256);
    short* Qb  = (short*)(ws + 256 + bufbf);
    short* Kb  = (short*)(ws + 256 + 2 * bufbf);
    short* Ab  = (short*)(ws + 256 + 4 * bufbf);
    short* Vtg = (short*)(ws + 256 + 5 * bufbf);
    short* Wqb = (short*)(ws + 256 + 6 * bufbf);
    short* Wkb = (short*)(ws + 256 + 6 * bufbf + wbuf);
    short* Wvb = (short*)(ws + 256 + 6 * bufbf + 2 * wbuf);
    short* Wob = (short*)(ws + 256 + 6 * bufbf + 3 * wbuf);

    constexpr int XBLK = (BATCH * SEQ * DIM / 4) / 256;  // 6144
    constexpr int WBLK = (DIM * DIM / 4) / 256;          // 576
    prep_kernel<<<XBLK + 4 * WBLK + 1, 256, 0, stream>>>(
        x, Wq, Wk, Wv, Wo, xb, Wqb, Wkb, Wvb, Wob,
        (const unsigned char*)ctx, BATCH * SEQ, flag);

    // Q scale = 0.125 * log2(e): scores arrive in exp2 domain.
    // V (z==2) is stored directly in the transposed+permuted Vtg layout.
    dim3 gQKV(DIM / 128, (BATCH * SEQ) / 128, 3);
    gemm_mfma<true, true><<<gQKV, 256, 0, stream>>>(
        xb, Wqb, bq, Qb, Wkb, bk, Kb, Wvb, bv, Vtg, 0.125f * 1.4426950408889634f);

    attn_mfma9<<<dim3(SEQ / 128 * NH * BATCH, 1, 1), 256, 0, stream>>>(
        Qb, Kb, Vtg, ctx, flag, Ab);

    dim3 gOut(DIM / 128, (BATCH * SEQ) / 128, 1);
    gemm_mfma<false, false><<<gOut, 256, 0, stream>>>(
        Ab, Wob, bo, out, Wob, bo, out, Wob, bo, out, 1.f);
}